// Round 7
// baseline (605.817 us; speedup 1.0000x reference)
//
#include <hip/hip_runtime.h>

// B=16, H=W=128. Compact NHWC bf16: xf1 64ch, xcv 96ch (81 cv + 15 zero),
// x1 128ch, x2 64ch, x3 32ch. Output [B,2,H,W] fp32 planar.

typedef __bf16 bf16x8 __attribute__((ext_vector_type(8)));
typedef float f32x4 __attribute__((ext_vector_type(4)));

__device__ __forceinline__ unsigned short f2bf_bits(float f) {
  unsigned int u = __float_as_uint(f);
  unsigned int r = (u + 0x7FFFu + ((u >> 16) & 1u)) >> 16;  // RNE
  return (unsigned short)r;
}

// ---------------- weight prepack: OIHW fp32 -> B-fragment lane order bf16 ----
__global__ void prep_w_kernel(const float* __restrict__ w, uint4* __restrict__ wp,
                              int CIN, int COUT, int CHUNKS, int NFRAG) {
  int idx = blockIdx.x * 256 + threadIdx.x;
  int total = CHUNKS * 9 * NFRAG * 64;
  if (idx >= total) return;
  int lane = idx & 63;
  int fi = idx >> 6;
  int nf = fi % NFRAG;
  int t = fi / NFRAG;
  int rs = t % 9;
  int c = t / 9;
  int co = nf * 16 + (lane & 15);
  int cib = c * 32 + (lane >> 4) * 8;
  union { uint4 q; ushort s[8]; } pk;
#pragma unroll
  for (int e = 0; e < 8; ++e) {
    int ci = cib + e;
    float v = (ci < CIN && co < COUT) ? w[(co * CIN + ci) * 9 + rs] : 0.f;
    pk.s[e] = f2bf_bits(v);
  }
  wp[idx] = pk.q;
}

// ---------------- f1 pack: NCHW fp32 -> compact NHWC bf16 (64 ch) -----------
__global__ __launch_bounds__(256) void pack_f1_kernel(const float* __restrict__ f1,
                                                      ushort* __restrict__ xf1) {
  __shared__ float tile[64][132];
  const int bid = blockIdx.x;
  const int h = bid & 127, b = bid >> 7;
  const int tid = threadIdx.x;
  for (int e = tid; e < 64 * 128; e += 256) {
    int c = e >> 7, w = e & 127;
    tile[c][w] = f1[((b * 64 + c) * 128 + h) * 128 + w];
  }
  __syncthreads();
  const int px = tid >> 1, cgb = (tid & 1) * 4;
  const long base = ((long)(b * 128 + h) * 128 + px) * 64;
#pragma unroll
  for (int e = 0; e < 4; ++e) {
    int c0 = (cgb + e) * 8;
    union { uint4 q; ushort s[8]; } pk;
#pragma unroll
    for (int k = 0; k < 8; ++k) pk.s[k] = f2bf_bits(tile[c0 + k][px]);
    *reinterpret_cast<uint4*>(&xf1[base + c0]) = pk.q;
  }
}

// ---------------- cost volume -> xcv compact NHWC (96 ch) -------------------
__global__ __launch_bounds__(256)
void cost_volume_kernel(const float* __restrict__ f1,
                        const float* __restrict__ f2,
                        ushort* __restrict__ xcv) {
  const int bx = blockIdx.x;           // 1024 blocks
  const int idx = bx >> 3;
  const int b = 2 * (bx & 7) + (idx >> 6);
  const int h0 = (idx & 63) * 2;
  const int tid = threadIdx.x;
  const int q = tid & 31;              // pixel quad: px 4q..4q+3
  const int rho = (tid >> 5) & 1;      // output row h0+rho
  const int g = tid >> 6;              // wave id

  __shared__ float arena[12480];

  float accF[2][9][4];
  float accP[3][4];
#pragma unroll
  for (int s = 0; s < 2; ++s)
#pragma unroll
    for (int jj = 0; jj < 9; ++jj)
#pragma unroll
      for (int e = 0; e < 4; ++e) accF[s][jj][e] = 0.f;
#pragma unroll
  for (int t = 0; t < 3; ++t)
#pragma unroll
    for (int e = 0; e < 4; ++e) accP[t][e] = 0.f;

  float st[13];

  auto stage = [&](int c) {
    const int cc = c * 2;
#pragma unroll
    for (int i = 0; i < 13; ++i) {
      int e = tid + i * 256;
      float v = 0.f;
      if (e < 2720) {
        int ci = e / 1360;
        int rem = e - ci * 1360;
        int a = rem / 136;
        int k = rem - a * 136;
        int gh = h0 - 4 + a, gw = k - 4;
        if ((unsigned)gh < 128u && (unsigned)gw < 128u)
          v = f2[((b * 64 + cc + ci) * 128 + gh) * 128 + gw];
      } else if (e < 3232) {
        int e2 = e - 2720;
        int ci = e2 >> 8, rr = (e2 >> 7) & 1, ww = e2 & 127;
        v = f1[((b * 64 + cc + ci) * 128 + h0 + rr) * 128 + ww];
      }
      st[i] = v;
    }
  };
  auto commit = [&](int bi) {
    float* bufp = arena + bi * 3232;
#pragma unroll
    for (int i = 0; i < 13; ++i) {
      int e = tid + i * 256;
      if (e < 3232) bufp[e] = st[i];
    }
  };

  stage(0);
  commit(0);

  for (int c = 0; c < 32; ++c) {
    __syncthreads();
    if (c < 31) stage(c + 1);
    const float* bufc = arena + (c & 1) * 3232;
#pragma unroll
    for (int ci = 0; ci < 2; ++ci) {
      const float* bp = bufc + ci * 1360;
      float4 f1q = *reinterpret_cast<const float4*>(bufc + 2720 + ci * 256 + rho * 128 + 4 * q);
      const float* f1e = &f1q.x;
#pragma unroll
      for (int s = 0; s < 2; ++s) {
        int a = rho + 8 - (2 * g + s);
        const float* rp = bp + a * 136 + 4 * q;
        float4 A = *reinterpret_cast<const float4*>(rp);
        float4 Bv = *reinterpret_cast<const float4*>(rp + 4);
        float4 Cv = *reinterpret_cast<const float4*>(rp + 8);
        float ev[12] = {A.x, A.y, A.z, A.w, Bv.x, Bv.y, Bv.z, Bv.w, Cv.x, Cv.y, Cv.z, Cv.w};
#pragma unroll
        for (int jj = 0; jj < 9; ++jj)
#pragma unroll
          for (int e = 0; e < 4; ++e)
            accF[s][jj][e] += f1e[e] * ev[8 - jj + e];
      }
      {
        const float* rp = bp + rho * 136 + 4 * q;
        if (g < 2) {
          float4 A = *reinterpret_cast<const float4*>(rp + 4);
          float4 Bv = *reinterpret_cast<const float4*>(rp + 8);
          float pv[8] = {A.x, A.y, A.z, A.w, Bv.x, Bv.y, Bv.z, Bv.w};
          if (g == 0) {
#pragma unroll
            for (int e = 0; e < 4; ++e) {
              accP[0][e] += f1e[e] * pv[4 + e];
              accP[1][e] += f1e[e] * pv[3 + e];
              accP[2][e] += f1e[e] * pv[2 + e];
            }
          } else {
#pragma unroll
            for (int e = 0; e < 4; ++e) {
              accP[0][e] += f1e[e] * pv[1 + e];
              accP[1][e] += f1e[e] * pv[e];
            }
          }
        } else {
          float4 A = *reinterpret_cast<const float4*>(rp);
          float4 Bv = *reinterpret_cast<const float4*>(rp + 4);
          float pv[8] = {A.x, A.y, A.z, A.w, Bv.x, Bv.y, Bv.z, Bv.w};
          if (g == 2) {
#pragma unroll
            for (int e = 0; e < 4; ++e) {
              accP[0][e] += f1e[e] * pv[3 + e];
              accP[1][e] += f1e[e] * pv[2 + e];
            }
          } else {
#pragma unroll
            for (int e = 0; e < 4; ++e) {
              accP[0][e] += f1e[e] * pv[1 + e];
              accP[1][e] += f1e[e] * pv[e];
            }
          }
        }
      }
    }
    if (c < 31) commit((c + 1) & 1);
  }

  __syncthreads();  // all compute done; overlay output staging
  ushort* sO = (ushort*)arena;  // [(r*96+ch)*130 + px]
  const float inv = 1.0f / 64.0f;
#pragma unroll
  for (int s = 0; s < 2; ++s) {
    int ch = (2 * g + s) * 9;
#pragma unroll
    for (int jj = 0; jj < 9; ++jj) {
      uint lo = (uint)f2bf_bits(accF[s][jj][0] * inv) | ((uint)f2bf_bits(accF[s][jj][1] * inv) << 16);
      uint hi = (uint)f2bf_bits(accF[s][jj][2] * inv) | ((uint)f2bf_bits(accF[s][jj][3] * inv) << 16);
      ushort* d = &sO[(rho * 96 + ch + jj) * 130 + 4 * q];
      *reinterpret_cast<uint*>(d) = lo;
      *reinterpret_cast<uint*>(d + 2) = hi;
    }
  }
  {
    const int npart = (g == 0) ? 3 : 2;
    const int chbase = 72 + ((g == 0) ? 0 : (g == 1) ? 3 : (g == 2) ? 5 : 7);
#pragma unroll
    for (int t = 0; t < 3; ++t) {
      if (t < npart) {
        uint lo = (uint)f2bf_bits(accP[t][0] * inv) | ((uint)f2bf_bits(accP[t][1] * inv) << 16);
        uint hi = (uint)f2bf_bits(accP[t][2] * inv) | ((uint)f2bf_bits(accP[t][3] * inv) << 16);
        ushort* d = &sO[(rho * 96 + chbase + t) * 130 + 4 * q];
        *reinterpret_cast<uint*>(d) = lo;
        *reinterpret_cast<uint*>(d + 2) = hi;
      }
    }
  }
  for (int e = tid; e < 1920; e += 256) {  // zero ch 81..95, both rows
    int r = e / 960;
    int rem = e - r * 960;
    int ch = 81 + (rem >> 6);
    int pxh = rem & 63;
    *reinterpret_cast<uint*>(&sO[(r * 96 + ch) * 130 + pxh * 2]) = 0u;
  }
  __syncthreads();

  // coalesced store: per row 1536 uint4 (128 px x 96 ch); 128 threads x 12 each
  {
    const int r = tid >> 7, u = tid & 127;
    uint4* dst = reinterpret_cast<uint4*>(xcv + ((long)(b * 128 + h0 + r) * 128) * 96);
#pragma unroll
    for (int j = 0; j < 12; ++j) {
      int t8 = 128 * j + u;           // 0..1535
      int px = t8 / 12;               // 0..127
      int ch0 = (t8 - px * 12) * 8;   // 0..88
      union { uint4 qq; ushort ss[8]; } pk;
#pragma unroll
      for (int k = 0; k < 8; ++k) pk.ss[k] = sO[(r * 96 + ch0 + k) * 130 + px];
      dst[t8] = pk.qq;
    }
  }
}

// ---------------- implicit-GEMM 3x3 conv via bf16 MFMA (2 rows, dbuf) -------
// Epilogue: LDS-staged transpose -> fully coalesced uint4 global stores.
template <int CA, int CB, int COUT, bool RELU, bool PLANAR>
__global__ __launch_bounds__(256, 2)
void conv_mfma_kernel(const ushort* __restrict__ xa, const ushort* __restrict__ xb,
                      const uint4* __restrict__ wp, const float* __restrict__ bias,
                      void* __restrict__ outv) {
  constexpr int CHUNKS = (CA + CB) / 32;
  constexpr int NFRAG = COUT / 16;
  constexpr int SXN = 4 * 130 * 32;              // ushorts per staging buffer
  constexpr int SO_STRIDE = COUT + 4;            // lg bank offset = 8 mod 32
  constexpr int STAGE_B = PLANAR ? 2048 : 2 * 128 * SO_STRIDE * 2;
  constexpr int SX_B = 2 * SXN * 2;              // 66560
  constexpr int ARENA_B = STAGE_B > SX_B ? STAGE_B : SX_B;

  __shared__ __align__(16) char arena[ARENA_B];
  ushort* sXa = (ushort*)arena;

  const int bx = blockIdx.x;              // 1024 blocks
  const int idx = bx >> 3;
  const int b = 2 * (bx & 7) + (idx >> 6);
  const int h0 = (idx & 63) * 2;
  const int tid = threadIdx.x;
  const int lane = tid & 63;
  const int wid = tid >> 6;
  const int m0 = wid * 32;
  const int l15 = lane & 15;
  const int lg = lane >> 4;

  f32x4 acc[4][NFRAG];
#pragma unroll
  for (int mf = 0; mf < 4; ++mf)
#pragma unroll
    for (int nf = 0; nf < NFRAG; ++nf) acc[mf][nf] = {0.f, 0.f, 0.f, 0.f};

  uint4 st[9];

  auto stage = [&](int c) {
    const int c0 = c * 32;
    const ushort* src;
    int cst, coff;
    if (CB == 0 || c0 < CA) { src = xa; cst = CA; coff = c0; }
    else                    { src = xb; cst = CB; coff = c0 - CA; }
#pragma unroll
    for (int i = 0; i < 9; ++i) {
      int e = tid + i * 256;
      if (e < 2080) {
        int row = e / 520;
        int rem = e - row * 520;
        int wl = rem >> 2;
        int gq = rem & 3;
        int gh = h0 - 1 + row, gw = wl - 1;
        uint4 v = make_uint4(0u, 0u, 0u, 0u);
        if ((unsigned)gh < 128u && (unsigned)gw < 128u)
          v = *reinterpret_cast<const uint4*>(
              &src[((long)(b * 128 + gh) * 128 + gw) * cst + coff + gq * 8]);
        st[i] = v;
      }
    }
  };
  auto commit = [&](int bi) {
#pragma unroll
    for (int i = 0; i < 9; ++i) {
      int e = tid + i * 256;
      if (e < 2080) {
        int row = e / 520;
        int rem = e - row * 520;
        int wl = rem >> 2;
        int gq = rem & 3;
        int sw = (wl + (wl >> 2)) & 3;
        *reinterpret_cast<uint4*>(&sXa[bi * SXN + ((row * 130 + wl) * 4 + (gq ^ sw)) * 8]) = st[i];
      }
    }
  };

  stage(0);
  commit(0);

  for (int c = 0; c < CHUNKS; ++c) {
    __syncthreads();
    if (c + 1 < CHUNKS) stage(c + 1);
    const int bi = c & 1;
#pragma unroll
    for (int rs = 0; rs < 9; ++rs) {
      const int r = rs / 3, s = rs % 3;
      bf16x8 afr[4];
#pragma unroll
      for (int mf = 0; mf < 4; ++mf) {
        int row = r + (mf >> 1);
        int wl = m0 + (mf & 1) * 16 + l15 + s;
        int sw = (wl + (wl >> 2)) & 3;
        afr[mf] = *reinterpret_cast<const bf16x8*>(
            &sXa[bi * SXN + ((row * 130 + wl) * 4 + (lg ^ sw)) * 8]);
      }
      const uint4* wb = wp + (size_t)((c * 9 + rs) * NFRAG) * 64 + lane;
#pragma unroll
      for (int nf = 0; nf < NFRAG; ++nf) {
        uint4 bw = wb[nf * 64];
        bf16x8 bfr = __builtin_bit_cast(bf16x8, bw);
#pragma unroll
        for (int mf = 0; mf < 4; ++mf)
          acc[mf][nf] = __builtin_amdgcn_mfma_f32_16x16x32_bf16(afr[mf], bfr, acc[mf][nf], 0, 0, 0);
      }
    }
    if (c + 1 < CHUNKS) commit((c + 1) & 1);
  }

  __syncthreads();  // staging buffers dead; overlay epilogue staging

  if (!PLANAR) {
    ushort* sO = (ushort*)arena;  // [px2][ch], stride SO_STRIDE; px2 = r*128+px
#pragma unroll
    for (int nf = 0; nf < NFRAG; ++nf) {
      float bs = bias[nf * 16 + l15];
#pragma unroll
      for (int mf = 0; mf < 4; ++mf) {
        int px2 = (mf >> 1) * 128 + m0 + (mf & 1) * 16 + lg * 4;
#pragma unroll
        for (int j = 0; j < 4; ++j) {
          float v = acc[mf][nf][j] + bs;
          if (RELU) v = fmaxf(v, 0.f);
          sO[(px2 + j) * SO_STRIDE + nf * 16 + l15] = f2bf_bits(v);
        }
      }
    }
    __syncthreads();
    // rows h0, h0+1 are contiguous in NHWC: one 2*128*COUT burst per block
    constexpr int QPP = COUT / 8;  // uint4 per pixel
    ushort* out = (ushort*)outv;
    uint4* dst = reinterpret_cast<uint4*>(out + ((long)(b * 128 + h0) * 128) * COUT);
#pragma unroll
    for (int t0 = 0; t0 < 2 * 128 * QPP / 256; ++t0) {
      int t = t0 * 256 + tid;
      int px2 = t / QPP;
      int ch0 = (t & (QPP - 1)) * 8;
      union { uint4 qq; ushort ss[8]; } pk;
#pragma unroll
      for (int k = 0; k < 8; ++k) pk.ss[k] = sO[px2 * SO_STRIDE + ch0 + k];
      dst[t] = pk.qq;
    }
  } else {
    float* sF = (float*)arena;  // [ch][r][px]
    if (l15 < 2) {
#pragma unroll
      for (int mf = 0; mf < 4; ++mf) {
        int r = mf >> 1;
        int pxb = m0 + (mf & 1) * 16 + lg * 4;
#pragma unroll
        for (int j = 0; j < 4; ++j)
          sF[(l15 * 2 + r) * 128 + pxb + j] = acc[mf][0][j] + bias[l15];
      }
    }
    __syncthreads();
    float* out = (float*)outv;
    if (tid < 128) {
      int ch = tid >> 6, r = (tid >> 5) & 1, qx = tid & 31;
      *reinterpret_cast<float4*>(&out[((long)(b * 2 + ch) * 128 + h0 + r) * 128 + qx * 4]) =
          *reinterpret_cast<float4*>(&sF[(ch * 2 + r) * 128 + qx * 4]);
    }
  }
}

extern "C" void kernel_launch(void* const* d_in, const int* in_sizes, int n_in,
                              void* d_out, int out_size, void* d_ws, size_t ws_size,
                              hipStream_t stream) {
  (void)in_sizes; (void)n_in; (void)out_size; (void)ws_size;
  const float* f1 = (const float*)d_in[0];
  const float* f2 = (const float*)d_in[1];
  const float* w1 = (const float*)d_in[2];
  const float* b1 = (const float*)d_in[3];
  const float* w2 = (const float*)d_in[4];
  const float* b2 = (const float*)d_in[5];
  const float* w3 = (const float*)d_in[6];
  const float* b3 = (const float*)d_in[7];
  const float* w4 = (const float*)d_in[8];
  const float* b4 = (const float*)d_in[9];

  char* ws = (char*)d_ws;
  size_t off = 0;
  ushort* xf1 = (ushort*)(ws + off); off += (size_t)262144 * 64 * 2;
  ushort* xcv = (ushort*)(ws + off); off += (size_t)262144 * 96 * 2;
  ushort* x1  = (ushort*)(ws + off); off += (size_t)262144 * 128 * 2;
  ushort* x2  = (ushort*)(ws + off); off += (size_t)262144 * 64 * 2;
  uint4* wp1 = (uint4*)(ws + off); off += (size_t)5 * 9 * 8 * 64 * 16;
  uint4* wp2 = (uint4*)(ws + off); off += (size_t)4 * 9 * 4 * 64 * 16;
  uint4* wp3 = (uint4*)(ws + off); off += (size_t)2 * 9 * 2 * 64 * 16;
  uint4* wp4 = (uint4*)(ws + off); off += (size_t)1 * 9 * 1 * 64 * 16;
  ushort* x3 = xf1;  // alias: xf1 fully consumed by conv1 before conv3 writes

  prep_w_kernel<<<90, 256, 0, stream>>>(w1, wp1, 145, 128, 5, 8);
  prep_w_kernel<<<36, 256, 0, stream>>>(w2, wp2, 128, 64, 4, 4);
  prep_w_kernel<<<9, 256, 0, stream>>>(w3, wp3, 64, 32, 2, 2);
  prep_w_kernel<<<3, 256, 0, stream>>>(w4, wp4, 32, 2, 1, 1);

  pack_f1_kernel<<<2048, 256, 0, stream>>>(f1, xf1);
  cost_volume_kernel<<<1024, 256, 0, stream>>>(f1, f2, xcv);

  conv_mfma_kernel<64, 96, 128, true, false><<<1024, 256, 0, stream>>>(xf1, xcv, wp1, b1, x1);
  conv_mfma_kernel<128, 0, 64, true, false><<<1024, 256, 0, stream>>>(x1, x1, wp2, b2, x2);
  conv_mfma_kernel<64, 0, 32, true, false><<<1024, 256, 0, stream>>>(x2, x2, wp3, b3, x3);
  conv_mfma_kernel<32, 0, 16, false, true><<<1024, 256, 0, stream>>>(x3, x3, wp4, b4, d_out);
}

// Round 8
// 493.614 us; speedup vs baseline: 1.2273x; 1.2273x over previous
//
#include <hip/hip_runtime.h>

// B=16, H=W=128. Compact NHWC bf16: xf1 64ch, xcv 96ch (81 cv + 15 zero),
// x1 128ch, x2 64ch, x3 32ch. Output [B,2,H,W] fp32 planar.

typedef __bf16 bf16x8 __attribute__((ext_vector_type(8)));
typedef float f32x4 __attribute__((ext_vector_type(4)));

__device__ __forceinline__ unsigned short f2bf_bits(float f) {
  unsigned int u = __float_as_uint(f);
  unsigned int r = (u + 0x7FFFu + ((u >> 16) & 1u)) >> 16;  // RNE
  return (unsigned short)r;
}

__device__ __forceinline__ void glds16(const ushort* gp, ushort* lp) {
  __builtin_amdgcn_global_load_lds((const __attribute__((address_space(1))) void*)gp,
                                   (__attribute__((address_space(3))) void*)lp, 16, 0, 0);
}

// ---------------- weight prepack: OIHW fp32 -> B-fragment lane order bf16 ----
__global__ void prep_w_kernel(const float* __restrict__ w, uint4* __restrict__ wp,
                              int CIN, int COUT, int CHUNKS, int NFRAG) {
  int idx = blockIdx.x * 256 + threadIdx.x;
  int total = CHUNKS * 9 * NFRAG * 64;
  if (idx >= total) return;
  int lane = idx & 63;
  int fi = idx >> 6;
  int nf = fi % NFRAG;
  int t = fi / NFRAG;
  int rs = t % 9;
  int c = t / 9;
  int co = nf * 16 + (lane & 15);
  int cib = c * 32 + (lane >> 4) * 8;
  union { uint4 q; ushort s[8]; } pk;
#pragma unroll
  for (int e = 0; e < 8; ++e) {
    int ci = cib + e;
    float v = (ci < CIN && co < COUT) ? w[(co * CIN + ci) * 9 + rs] : 0.f;
    pk.s[e] = f2bf_bits(v);
  }
  wp[idx] = pk.q;
}

// ---------------- f1 pack: NCHW fp32 -> compact NHWC bf16 (64 ch) -----------
__global__ __launch_bounds__(256) void pack_f1_kernel(const float* __restrict__ f1,
                                                      ushort* __restrict__ xf1) {
  __shared__ float tile[64][132];
  const int bid = blockIdx.x;
  const int h = bid & 127, b = bid >> 7;
  const int tid = threadIdx.x;
  for (int e = tid; e < 64 * 128; e += 256) {
    int c = e >> 7, w = e & 127;
    tile[c][w] = f1[((b * 64 + c) * 128 + h) * 128 + w];
  }
  __syncthreads();
  const int px = tid >> 1, cgb = (tid & 1) * 4;
  const long base = ((long)(b * 128 + h) * 128 + px) * 64;
#pragma unroll
  for (int e = 0; e < 4; ++e) {
    int c0 = (cgb + e) * 8;
    union { uint4 q; ushort s[8]; } pk;
#pragma unroll
    for (int k = 0; k < 8; ++k) pk.s[k] = f2bf_bits(tile[c0 + k][px]);
    *reinterpret_cast<uint4*>(&xf1[base + c0]) = pk.q;
  }
}

// ---------------- cost volume -> xcv compact NHWC (96 ch) -------------------
__global__ __launch_bounds__(256)
void cost_volume_kernel(const float* __restrict__ f1,
                        const float* __restrict__ f2,
                        ushort* __restrict__ xcv) {
  const int bx = blockIdx.x;           // 1024 blocks
  const int idx = bx >> 3;
  const int b = 2 * (bx & 7) + (idx >> 6);
  const int h0 = (idx & 63) * 2;
  const int tid = threadIdx.x;
  const int q = tid & 31;              // pixel quad: px 4q..4q+3
  const int rho = (tid >> 5) & 1;      // output row h0+rho
  const int g = tid >> 6;              // wave id

  __shared__ float arena[12480];

  float accF[2][9][4];
  float accP[3][4];
#pragma unroll
  for (int s = 0; s < 2; ++s)
#pragma unroll
    for (int jj = 0; jj < 9; ++jj)
#pragma unroll
      for (int e = 0; e < 4; ++e) accF[s][jj][e] = 0.f;
#pragma unroll
  for (int t = 0; t < 3; ++t)
#pragma unroll
    for (int e = 0; e < 4; ++e) accP[t][e] = 0.f;

  float st[13];

  auto stage = [&](int c) {
    const int cc = c * 2;
#pragma unroll
    for (int i = 0; i < 13; ++i) {
      int e = tid + i * 256;
      float v = 0.f;
      if (e < 2720) {
        int ci = e / 1360;
        int rem = e - ci * 1360;
        int a = rem / 136;
        int k = rem - a * 136;
        int gh = h0 - 4 + a, gw = k - 4;
        if ((unsigned)gh < 128u && (unsigned)gw < 128u)
          v = f2[((b * 64 + cc + ci) * 128 + gh) * 128 + gw];
      } else if (e < 3232) {
        int e2 = e - 2720;
        int ci = e2 >> 8, rr = (e2 >> 7) & 1, ww = e2 & 127;
        v = f1[((b * 64 + cc + ci) * 128 + h0 + rr) * 128 + ww];
      }
      st[i] = v;
    }
  };
  auto commit = [&](int bi) {
    float* bufp = arena + bi * 3232;
#pragma unroll
    for (int i = 0; i < 13; ++i) {
      int e = tid + i * 256;
      if (e < 3232) bufp[e] = st[i];
    }
  };

  stage(0);
  commit(0);

  for (int c = 0; c < 32; ++c) {
    __syncthreads();
    if (c < 31) stage(c + 1);
    const float* bufc = arena + (c & 1) * 3232;
#pragma unroll
    for (int ci = 0; ci < 2; ++ci) {
      const float* bp = bufc + ci * 1360;
      float4 f1q = *reinterpret_cast<const float4*>(bufc + 2720 + ci * 256 + rho * 128 + 4 * q);
      const float* f1e = &f1q.x;
#pragma unroll
      for (int s = 0; s < 2; ++s) {
        int a = rho + 8 - (2 * g + s);
        const float* rp = bp + a * 136 + 4 * q;
        float4 A = *reinterpret_cast<const float4*>(rp);
        float4 Bv = *reinterpret_cast<const float4*>(rp + 4);
        float4 Cv = *reinterpret_cast<const float4*>(rp + 8);
        float ev[12] = {A.x, A.y, A.z, A.w, Bv.x, Bv.y, Bv.z, Bv.w, Cv.x, Cv.y, Cv.z, Cv.w};
#pragma unroll
        for (int jj = 0; jj < 9; ++jj)
#pragma unroll
          for (int e = 0; e < 4; ++e)
            accF[s][jj][e] += f1e[e] * ev[8 - jj + e];
      }
      {
        const float* rp = bp + rho * 136 + 4 * q;
        if (g < 2) {
          float4 A = *reinterpret_cast<const float4*>(rp + 4);
          float4 Bv = *reinterpret_cast<const float4*>(rp + 8);
          float pv[8] = {A.x, A.y, A.z, A.w, Bv.x, Bv.y, Bv.z, Bv.w};
          if (g == 0) {
#pragma unroll
            for (int e = 0; e < 4; ++e) {
              accP[0][e] += f1e[e] * pv[4 + e];
              accP[1][e] += f1e[e] * pv[3 + e];
              accP[2][e] += f1e[e] * pv[2 + e];
            }
          } else {
#pragma unroll
            for (int e = 0; e < 4; ++e) {
              accP[0][e] += f1e[e] * pv[1 + e];
              accP[1][e] += f1e[e] * pv[e];
            }
          }
        } else {
          float4 A = *reinterpret_cast<const float4*>(rp);
          float4 Bv = *reinterpret_cast<const float4*>(rp + 4);
          float pv[8] = {A.x, A.y, A.z, A.w, Bv.x, Bv.y, Bv.z, Bv.w};
          if (g == 2) {
#pragma unroll
            for (int e = 0; e < 4; ++e) {
              accP[0][e] += f1e[e] * pv[3 + e];
              accP[1][e] += f1e[e] * pv[2 + e];
            }
          } else {
#pragma unroll
            for (int e = 0; e < 4; ++e) {
              accP[0][e] += f1e[e] * pv[1 + e];
              accP[1][e] += f1e[e] * pv[e];
            }
          }
        }
      }
    }
    if (c < 31) commit((c + 1) & 1);
  }

  __syncthreads();  // all compute done; overlay output staging
  ushort* sO = (ushort*)arena;  // [(r*96+ch)*130 + px]
  const float inv = 1.0f / 64.0f;
#pragma unroll
  for (int s = 0; s < 2; ++s) {
    int ch = (2 * g + s) * 9;
#pragma unroll
    for (int jj = 0; jj < 9; ++jj) {
      uint lo = (uint)f2bf_bits(accF[s][jj][0] * inv) | ((uint)f2bf_bits(accF[s][jj][1] * inv) << 16);
      uint hi = (uint)f2bf_bits(accF[s][jj][2] * inv) | ((uint)f2bf_bits(accF[s][jj][3] * inv) << 16);
      ushort* d = &sO[(rho * 96 + ch + jj) * 130 + 4 * q];
      *reinterpret_cast<uint*>(d) = lo;
      *reinterpret_cast<uint*>(d + 2) = hi;
    }
  }
  {
    const int npart = (g == 0) ? 3 : 2;
    const int chbase = 72 + ((g == 0) ? 0 : (g == 1) ? 3 : (g == 2) ? 5 : 7);
#pragma unroll
    for (int t = 0; t < 3; ++t) {
      if (t < npart) {
        uint lo = (uint)f2bf_bits(accP[t][0] * inv) | ((uint)f2bf_bits(accP[t][1] * inv) << 16);
        uint hi = (uint)f2bf_bits(accP[t][2] * inv) | ((uint)f2bf_bits(accP[t][3] * inv) << 16);
        ushort* d = &sO[(rho * 96 + chbase + t) * 130 + 4 * q];
        *reinterpret_cast<uint*>(d) = lo;
        *reinterpret_cast<uint*>(d + 2) = hi;
      }
    }
  }
  for (int e = tid; e < 1920; e += 256) {  // zero ch 81..95, both rows
    int r = e / 960;
    int rem = e - r * 960;
    int ch = 81 + (rem >> 6);
    int pxh = rem & 63;
    *reinterpret_cast<uint*>(&sO[(r * 96 + ch) * 130 + pxh * 2]) = 0u;
  }
  __syncthreads();

  // coalesced store: per row 1536 uint4 (128 px x 96 ch); 128 threads x 12 each
  {
    const int r = tid >> 7, u = tid & 127;
    uint4* dst = reinterpret_cast<uint4*>(xcv + ((long)(b * 128 + h0 + r) * 128) * 96);
#pragma unroll
    for (int j = 0; j < 12; ++j) {
      int t8 = 128 * j + u;           // 0..1535
      int px = t8 / 12;               // 0..127
      int ch0 = (t8 - px * 12) * 8;   // 0..88
      union { uint4 qq; ushort ss[8]; } pk;
#pragma unroll
      for (int k = 0; k < 8; ++k) pk.ss[k] = sO[(r * 96 + ch0 + k) * 130 + px];
      dst[t8] = pk.qq;
    }
  }
}

// ---------------- implicit-GEMM 3x3 conv via bf16 MFMA ----------------------
// 512 thr = 8 waves; wave = 1 output row x 32 px (2 M-frags) x all N-frags.
// Staging: global_load_lds (16B) with pre-swizzled per-lane source; LDS dest
// linear; pads (wl=0,129; OOB rows) zeroed once, never overwritten (chunk-
// invariant). Double-buffered. Epilogue: LDS transpose -> coalesced uint4.
template <int CA, int CB, int COUT, bool RELU, bool PLANAR>
__global__ __launch_bounds__(512, 4)
void conv_mfma_kernel(const ushort* __restrict__ xa, const ushort* __restrict__ xb,
                      const uint4* __restrict__ wp, const float* __restrict__ bias,
                      void* __restrict__ outv) {
  constexpr int CHUNKS = (CA + CB) / 32;
  constexpr int NFRAG = COUT / 16;
  constexpr int SXN = 4 * 130 * 32;              // ushorts per staging buffer
  constexpr int SO_STRIDE = COUT + 4;
  constexpr int STAGE_B = PLANAR ? 2048 : 2 * 128 * SO_STRIDE * 2;
  constexpr int SX_B = 2 * SXN * 2;              // 66560
  constexpr int ARENA_B = STAGE_B > SX_B ? STAGE_B : SX_B;

  __shared__ __align__(16) char arena[ARENA_B];
  ushort* sXa = (ushort*)arena;

  const int bx = blockIdx.x;              // 1024 blocks
  const int idx = bx >> 3;
  const int b = 2 * (bx & 7) + (idx >> 6);
  const int h0 = (idx & 63) * 2;
  const int tid = threadIdx.x;
  const int lane = tid & 63;
  const int wid = tid >> 6;               // 0..7
  const int row = wid >> 2;               // output row h0+row
  const int m0 = (wid & 3) * 32;          // pixel base within row
  const int l15 = lane & 15;
  const int lg = lane >> 4;

  f32x4 acc[2][NFRAG];
#pragma unroll
  for (int mf = 0; mf < 2; ++mf)
#pragma unroll
    for (int nf = 0; nf < NFRAG; ++nf) acc[mf][nf] = {0.f, 0.f, 0.f, 0.f};

  // zero chunk-invariant pad slots: wl=0 and wl=129, all 4 tilerows, both bufs
  if (tid < 64) {
    int bi = tid >> 5, tr = (tid >> 3) & 3, wz = (tid >> 2) & 1, gq = tid & 3;
    int wl = wz ? 129 : 0;
    *reinterpret_cast<uint4*>(&sXa[bi * SXN + ((tr * 130 + wl) * 4 + gq) * 8]) =
        make_uint4(0u, 0u, 0u, 0u);
  }
  // zero OOB rows (boundary blocks only); loads skip them every chunk
  if (h0 == 0 || h0 == 126) {
    const int trz = (h0 == 0) ? 0 : 3;
#pragma unroll
    for (int e = 0; e < 2; ++e) {
      int u = tid + e * 512;  // 0..1023 -> bi = u>>9, within-row uint4 idx u&511
      int bi = u >> 9, k = u & 511;
      *reinterpret_cast<uint4*>(&sXa[bi * SXN + ((trz * 130 + 1) * 4 + k) * 8]) =
          make_uint4(0u, 0u, 0u, 0u);
    }
  }

  // async stage chunk c into buffer bi: per wave 4 x glds16 (1 tilerow half)
  auto stage = [&](int c, int bi) {
    const int c0 = c * 32;
    const ushort* src;
    int cst, coff;
    if (CB == 0 || c0 < CA) { src = xa; cst = CA; coff = c0; }
    else                    { src = xb; cst = CB; coff = c0 - CA; }
    const int tr = wid >> 1;            // tilerow 0..3
    const int gh = h0 - 1 + tr;
    if ((unsigned)gh < 128u) {
      const ushort* rowp = src + ((long)(b * 128 + gh) * 128) * cst + coff;
#pragma unroll
      for (int t = 0; t < 4; ++t) {
        int s = (wid & 1) * 4 + t;      // segment 0..7 within tilerow
        int u = s * 64 + lane;          // uint4 idx within row region (0..511)
        int wl = 1 + (u >> 2);
        int gq = lane & 3;
        int sw = (wl + (wl >> 2)) & 3;
        const ushort* gp = rowp + (long)(wl - 1) * cst + (gq ^ sw) * 8;
        ushort* lp = &sXa[bi * SXN + ((tr * 130 + 1) * 4 + s * 64) * 8];
        glds16(gp, lp);
      }
    }
  };

  stage(0, 0);

  for (int c = 0; c < CHUNKS; ++c) {
    __syncthreads();                    // drains vmcnt: buf[c&1] ready
    if (c + 1 < CHUNKS) stage(c + 1, (c + 1) & 1);
    const int bi = c & 1;
#pragma unroll
    for (int rs = 0; rs < 9; ++rs) {
      const int r = rs / 3, s = rs % 3;
      const int tr = row + r;
      bf16x8 afr[2];
#pragma unroll
      for (int mf = 0; mf < 2; ++mf) {
        int wl = m0 + mf * 16 + l15 + s;
        int sw = (wl + (wl >> 2)) & 3;
        afr[mf] = *reinterpret_cast<const bf16x8*>(
            &sXa[bi * SXN + ((tr * 130 + wl) * 4 + (lg ^ sw)) * 8]);
      }
      const uint4* wb = wp + (size_t)((c * 9 + rs) * NFRAG) * 64 + lane;
#pragma unroll
      for (int nf = 0; nf < NFRAG; ++nf) {
        bf16x8 bfr = __builtin_bit_cast(bf16x8, wb[nf * 64]);
        acc[0][nf] = __builtin_amdgcn_mfma_f32_16x16x32_bf16(afr[0], bfr, acc[0][nf], 0, 0, 0);
        acc[1][nf] = __builtin_amdgcn_mfma_f32_16x16x32_bf16(afr[1], bfr, acc[1][nf], 0, 0, 0);
      }
    }
  }

  __syncthreads();  // staging buffers dead; overlay epilogue staging

  if (!PLANAR) {
    ushort* sO = (ushort*)arena;  // [px2][ch], stride SO_STRIDE; px2 = row*128+px
#pragma unroll
    for (int nf = 0; nf < NFRAG; ++nf) {
      float bs = bias[nf * 16 + l15];
#pragma unroll
      for (int mf = 0; mf < 2; ++mf) {
        int px2 = row * 128 + m0 + mf * 16 + lg * 4;
#pragma unroll
        for (int j = 0; j < 4; ++j) {
          float v = acc[mf][nf][j] + bs;
          if (RELU) v = fmaxf(v, 0.f);
          sO[(px2 + j) * SO_STRIDE + nf * 16 + l15] = f2bf_bits(v);
        }
      }
    }
    __syncthreads();
    constexpr int QPP = COUT / 8;  // uint4 per pixel
    uint4* dst = reinterpret_cast<uint4*>((ushort*)outv + ((long)(b * 128 + h0) * 128) * COUT);
#pragma unroll
    for (int t0 = 0; t0 < 2 * 128 * QPP / 512; ++t0) {
      int t = t0 * 512 + tid;
      int px2 = t / QPP;
      int ch0 = (t & (QPP - 1)) * 8;
      union { uint4 qq; ushort ss[8]; } pk;
#pragma unroll
      for (int k = 0; k < 8; ++k) pk.ss[k] = sO[px2 * SO_STRIDE + ch0 + k];
      dst[t] = pk.qq;
    }
  } else {
    float* sF = (float*)arena;  // [ch][r][px]
    if (l15 < 2) {
#pragma unroll
      for (int mf = 0; mf < 2; ++mf) {
        int pxb = m0 + mf * 16 + lg * 4;
#pragma unroll
        for (int j = 0; j < 4; ++j)
          sF[(l15 * 2 + row) * 128 + pxb + j] = acc[mf][0][j] + bias[l15];
      }
    }
    __syncthreads();
    float* out = (float*)outv;
    if (tid < 128) {
      int ch = tid >> 6, r = (tid >> 5) & 1, qx = tid & 31;
      *reinterpret_cast<float4*>(&out[((long)(b * 2 + ch) * 128 + h0 + r) * 128 + qx * 4]) =
          *reinterpret_cast<float4*>(&sF[(ch * 2 + r) * 128 + qx * 4]);
    }
  }
}

extern "C" void kernel_launch(void* const* d_in, const int* in_sizes, int n_in,
                              void* d_out, int out_size, void* d_ws, size_t ws_size,
                              hipStream_t stream) {
  (void)in_sizes; (void)n_in; (void)out_size; (void)ws_size;
  const float* f1 = (const float*)d_in[0];
  const float* f2 = (const float*)d_in[1];
  const float* w1 = (const float*)d_in[2];
  const float* b1 = (const float*)d_in[3];
  const float* w2 = (const float*)d_in[4];
  const float* b2 = (const float*)d_in[5];
  const float* w3 = (const float*)d_in[6];
  const float* b3 = (const float*)d_in[7];
  const float* w4 = (const float*)d_in[8];
  const float* b4 = (const float*)d_in[9];

  char* ws = (char*)d_ws;
  size_t off = 0;
  ushort* xf1 = (ushort*)(ws + off); off += (size_t)262144 * 64 * 2;
  ushort* xcv = (ushort*)(ws + off); off += (size_t)262144 * 96 * 2;
  ushort* x1  = (ushort*)(ws + off); off += (size_t)262144 * 128 * 2;
  ushort* x2  = (ushort*)(ws + off); off += (size_t)262144 * 64 * 2;
  uint4* wp1 = (uint4*)(ws + off); off += (size_t)5 * 9 * 8 * 64 * 16;
  uint4* wp2 = (uint4*)(ws + off); off += (size_t)4 * 9 * 4 * 64 * 16;
  uint4* wp3 = (uint4*)(ws + off); off += (size_t)2 * 9 * 2 * 64 * 16;
  uint4* wp4 = (uint4*)(ws + off); off += (size_t)1 * 9 * 1 * 64 * 16;
  ushort* x3 = xf1;  // alias: xf1 fully consumed by conv1 before conv3 writes

  prep_w_kernel<<<90, 256, 0, stream>>>(w1, wp1, 145, 128, 5, 8);
  prep_w_kernel<<<36, 256, 0, stream>>>(w2, wp2, 128, 64, 4, 4);
  prep_w_kernel<<<9, 256, 0, stream>>>(w3, wp3, 64, 32, 2, 2);
  prep_w_kernel<<<3, 256, 0, stream>>>(w4, wp4, 32, 2, 1, 1);

  pack_f1_kernel<<<2048, 256, 0, stream>>>(f1, xf1);
  cost_volume_kernel<<<1024, 256, 0, stream>>>(f1, f2, xcv);

  conv_mfma_kernel<64, 96, 128, true, false><<<1024, 512, 0, stream>>>(xf1, xcv, wp1, b1, x1);
  conv_mfma_kernel<128, 0, 64, true, false><<<1024, 512, 0, stream>>>(x1, x1, wp2, b2, x2);
  conv_mfma_kernel<64, 0, 32, true, false><<<1024, 512, 0, stream>>>(x2, x2, wp3, b3, x3);
  conv_mfma_kernel<32, 0, 16, false, true><<<1024, 512, 0, stream>>>(x3, x3, wp4, b4, d_out);
}

// Round 9
// 466.366 us; speedup vs baseline: 1.2990x; 1.0584x over previous
//
#include <hip/hip_runtime.h>

// B=16, H=W=128. Compact NHWC bf16: xf1 64ch, xcv 96ch (81 cv + 15 zero),
// x1 128ch, x2 64ch, x3 32ch. Output [B,2,H,W] fp32 planar.

typedef __bf16 bf16x8 __attribute__((ext_vector_type(8)));
typedef float f32x4 __attribute__((ext_vector_type(4)));

__device__ __forceinline__ unsigned short f2bf_bits(float f) {
  unsigned int u = __float_as_uint(f);
  unsigned int r = (u + 0x7FFFu + ((u >> 16) & 1u)) >> 16;  // RNE
  return (unsigned short)r;
}

__device__ __forceinline__ void glds16(const ushort* gp, ushort* lp) {
  __builtin_amdgcn_global_load_lds((const __attribute__((address_space(1))) void*)gp,
                                   (__attribute__((address_space(3))) void*)lp, 16, 0, 0);
}

// ---------------- weight prepack: OIHW fp32 -> B-fragment lane order bf16 ----
__global__ void prep_w_kernel(const float* __restrict__ w, uint4* __restrict__ wp,
                              int CIN, int COUT, int CHUNKS, int NFRAG) {
  int idx = blockIdx.x * 256 + threadIdx.x;
  int total = CHUNKS * 9 * NFRAG * 64;
  if (idx >= total) return;
  int lane = idx & 63;
  int fi = idx >> 6;
  int nf = fi % NFRAG;
  int t = fi / NFRAG;
  int rs = t % 9;
  int c = t / 9;
  int co = nf * 16 + (lane & 15);
  int cib = c * 32 + (lane >> 4) * 8;
  union { uint4 q; ushort s[8]; } pk;
#pragma unroll
  for (int e = 0; e < 8; ++e) {
    int ci = cib + e;
    float v = (ci < CIN && co < COUT) ? w[(co * CIN + ci) * 9 + rs] : 0.f;
    pk.s[e] = f2bf_bits(v);
  }
  wp[idx] = pk.q;
}

// ---------------- f1 pack: NCHW fp32 -> compact NHWC bf16 (64 ch) -----------
__global__ __launch_bounds__(256) void pack_f1_kernel(const float* __restrict__ f1,
                                                      ushort* __restrict__ xf1) {
  __shared__ float tile[64][132];
  const int bid = blockIdx.x;
  const int h = bid & 127, b = bid >> 7;
  const int tid = threadIdx.x;
  for (int e = tid; e < 64 * 128; e += 256) {
    int c = e >> 7, w = e & 127;
    tile[c][w] = f1[((b * 64 + c) * 128 + h) * 128 + w];
  }
  __syncthreads();
  const int px = tid >> 1, cgb = (tid & 1) * 4;
  const long base = ((long)(b * 128 + h) * 128 + px) * 64;
#pragma unroll
  for (int e = 0; e < 4; ++e) {
    int c0 = (cgb + e) * 8;
    union { uint4 q; ushort s[8]; } pk;
#pragma unroll
    for (int k = 0; k < 8; ++k) pk.s[k] = f2bf_bits(tile[c0 + k][px]);
    *reinterpret_cast<uint4*>(&xf1[base + c0]) = pk.q;
  }
}

// ---------------- cost volume -> xcv compact NHWC (96 ch) -------------------
__global__ __launch_bounds__(256)
void cost_volume_kernel(const float* __restrict__ f1,
                        const float* __restrict__ f2,
                        ushort* __restrict__ xcv) {
  const int bx = blockIdx.x;           // 1024 blocks
  const int idx = bx >> 3;
  const int b = 2 * (bx & 7) + (idx >> 6);
  const int h0 = (idx & 63) * 2;
  const int tid = threadIdx.x;
  const int q = tid & 31;              // pixel quad: px 4q..4q+3
  const int rho = (tid >> 5) & 1;      // output row h0+rho
  const int g = tid >> 6;              // wave id

  __shared__ float arena[12480];

  float accF[2][9][4];
  float accP[3][4];
#pragma unroll
  for (int s = 0; s < 2; ++s)
#pragma unroll
    for (int jj = 0; jj < 9; ++jj)
#pragma unroll
      for (int e = 0; e < 4; ++e) accF[s][jj][e] = 0.f;
#pragma unroll
  for (int t = 0; t < 3; ++t)
#pragma unroll
    for (int e = 0; e < 4; ++e) accP[t][e] = 0.f;

  float st[13];

  auto stage = [&](int c) {
    const int cc = c * 2;
#pragma unroll
    for (int i = 0; i < 13; ++i) {
      int e = tid + i * 256;
      float v = 0.f;
      if (e < 2720) {
        int ci = e / 1360;
        int rem = e - ci * 1360;
        int a = rem / 136;
        int k = rem - a * 136;
        int gh = h0 - 4 + a, gw = k - 4;
        if ((unsigned)gh < 128u && (unsigned)gw < 128u)
          v = f2[((b * 64 + cc + ci) * 128 + gh) * 128 + gw];
      } else if (e < 3232) {
        int e2 = e - 2720;
        int ci = e2 >> 8, rr = (e2 >> 7) & 1, ww = e2 & 127;
        v = f1[((b * 64 + cc + ci) * 128 + h0 + rr) * 128 + ww];
      }
      st[i] = v;
    }
  };
  auto commit = [&](int bi) {
    float* bufp = arena + bi * 3232;
#pragma unroll
    for (int i = 0; i < 13; ++i) {
      int e = tid + i * 256;
      if (e < 3232) bufp[e] = st[i];
    }
  };

  stage(0);
  commit(0);

  for (int c = 0; c < 32; ++c) {
    __syncthreads();
    if (c < 31) stage(c + 1);
    const float* bufc = arena + (c & 1) * 3232;
#pragma unroll
    for (int ci = 0; ci < 2; ++ci) {
      const float* bp = bufc + ci * 1360;
      float4 f1q = *reinterpret_cast<const float4*>(bufc + 2720 + ci * 256 + rho * 128 + 4 * q);
      const float* f1e = &f1q.x;
#pragma unroll
      for (int s = 0; s < 2; ++s) {
        int a = rho + 8 - (2 * g + s);
        const float* rp = bp + a * 136 + 4 * q;
        float4 A = *reinterpret_cast<const float4*>(rp);
        float4 Bv = *reinterpret_cast<const float4*>(rp + 4);
        float4 Cv = *reinterpret_cast<const float4*>(rp + 8);
        float ev[12] = {A.x, A.y, A.z, A.w, Bv.x, Bv.y, Bv.z, Bv.w, Cv.x, Cv.y, Cv.z, Cv.w};
#pragma unroll
        for (int jj = 0; jj < 9; ++jj)
#pragma unroll
          for (int e = 0; e < 4; ++e)
            accF[s][jj][e] += f1e[e] * ev[8 - jj + e];
      }
      {
        const float* rp = bp + rho * 136 + 4 * q;
        if (g < 2) {
          float4 A = *reinterpret_cast<const float4*>(rp + 4);
          float4 Bv = *reinterpret_cast<const float4*>(rp + 8);
          float pv[8] = {A.x, A.y, A.z, A.w, Bv.x, Bv.y, Bv.z, Bv.w};
          if (g == 0) {
#pragma unroll
            for (int e = 0; e < 4; ++e) {
              accP[0][e] += f1e[e] * pv[4 + e];
              accP[1][e] += f1e[e] * pv[3 + e];
              accP[2][e] += f1e[e] * pv[2 + e];
            }
          } else {
#pragma unroll
            for (int e = 0; e < 4; ++e) {
              accP[0][e] += f1e[e] * pv[1 + e];
              accP[1][e] += f1e[e] * pv[e];
            }
          }
        } else {
          float4 A = *reinterpret_cast<const float4*>(rp);
          float4 Bv = *reinterpret_cast<const float4*>(rp + 4);
          float pv[8] = {A.x, A.y, A.z, A.w, Bv.x, Bv.y, Bv.z, Bv.w};
          if (g == 2) {
#pragma unroll
            for (int e = 0; e < 4; ++e) {
              accP[0][e] += f1e[e] * pv[3 + e];
              accP[1][e] += f1e[e] * pv[2 + e];
            }
          } else {
#pragma unroll
            for (int e = 0; e < 4; ++e) {
              accP[0][e] += f1e[e] * pv[1 + e];
              accP[1][e] += f1e[e] * pv[e];
            }
          }
        }
      }
    }
    if (c < 31) commit((c + 1) & 1);
  }

  __syncthreads();  // all compute done; overlay output staging
  ushort* sO = (ushort*)arena;  // [(r*96+ch)*130 + px]
  const float inv = 1.0f / 64.0f;
#pragma unroll
  for (int s = 0; s < 2; ++s) {
    int ch = (2 * g + s) * 9;
#pragma unroll
    for (int jj = 0; jj < 9; ++jj) {
      uint lo = (uint)f2bf_bits(accF[s][jj][0] * inv) | ((uint)f2bf_bits(accF[s][jj][1] * inv) << 16);
      uint hi = (uint)f2bf_bits(accF[s][jj][2] * inv) | ((uint)f2bf_bits(accF[s][jj][3] * inv) << 16);
      ushort* d = &sO[(rho * 96 + ch + jj) * 130 + 4 * q];
      *reinterpret_cast<uint*>(d) = lo;
      *reinterpret_cast<uint*>(d + 2) = hi;
    }
  }
  {
    const int npart = (g == 0) ? 3 : 2;
    const int chbase = 72 + ((g == 0) ? 0 : (g == 1) ? 3 : (g == 2) ? 5 : 7);
#pragma unroll
    for (int t = 0; t < 3; ++t) {
      if (t < npart) {
        uint lo = (uint)f2bf_bits(accP[t][0] * inv) | ((uint)f2bf_bits(accP[t][1] * inv) << 16);
        uint hi = (uint)f2bf_bits(accP[t][2] * inv) | ((uint)f2bf_bits(accP[t][3] * inv) << 16);
        ushort* d = &sO[(rho * 96 + chbase + t) * 130 + 4 * q];
        *reinterpret_cast<uint*>(d) = lo;
        *reinterpret_cast<uint*>(d + 2) = hi;
      }
    }
  }
  for (int e = tid; e < 1920; e += 256) {  // zero ch 81..95, both rows
    int r = e / 960;
    int rem = e - r * 960;
    int ch = 81 + (rem >> 6);
    int pxh = rem & 63;
    *reinterpret_cast<uint*>(&sO[(r * 96 + ch) * 130 + pxh * 2]) = 0u;
  }
  __syncthreads();

  // coalesced store: per row 1536 uint4 (128 px x 96 ch); 128 threads x 12 each
  {
    const int r = tid >> 7, u = tid & 127;
    uint4* dst = reinterpret_cast<uint4*>(xcv + ((long)(b * 128 + h0 + r) * 128) * 96);
#pragma unroll
    for (int j = 0; j < 12; ++j) {
      int t8 = 128 * j + u;           // 0..1535
      int px = t8 / 12;               // 0..127
      int ch0 = (t8 - px * 12) * 8;   // 0..88
      union { uint4 qq; ushort ss[8]; } pk;
#pragma unroll
      for (int k = 0; k < 8; ++k) pk.ss[k] = sO[(r * 96 + ch0 + k) * 130 + px];
      dst[t8] = pk.qq;
    }
  }
}

// ---------------- implicit-GEMM 3x3 conv via bf16 MFMA ----------------------
// 512 thr = 8 waves; wave = 1 output row x 32 px (2 M-frags) x all N-frags.
// Activations: glds16 double-buffer (pre-swizzled source, linear dest).
// Weights: global->reg during compute(c), ds_write after barrier -> LDS single
// buffer; inner loop is pure ds_read_b128 + MFMA (both operands from LDS).
template <int CA, int CB, int COUT, bool RELU, bool PLANAR>
__global__ __launch_bounds__(512, 2)
void conv_mfma_kernel(const ushort* __restrict__ xa, const ushort* __restrict__ xb,
                      const uint4* __restrict__ wp, const float* __restrict__ bias,
                      void* __restrict__ outv) {
  constexpr int CHUNKS = (CA + CB) / 32;
  constexpr int NFRAG = COUT / 16;
  constexpr int SXN = 4 * 130 * 32;              // ushorts per act buffer
  constexpr int WTQ = 9 * NFRAG * 64;            // uint4 per weight chunk
  constexpr int WI = (WTQ + 511) / 512;          // per-thread staged uint4
  constexpr int SO_STRIDE = COUT + 4;
  constexpr int STAGE_B = PLANAR ? 2048 : 2 * 128 * SO_STRIDE * 2;
  constexpr int SX_B = 2 * SXN * 2;              // 66560
  constexpr int BASE_B = SX_B + WTQ * 16;        // act dbuf + wt buf
  constexpr int ARENA_B = STAGE_B > BASE_B ? STAGE_B : BASE_B;

  __shared__ __align__(16) char arena[ARENA_B];
  ushort* sXa = (ushort*)arena;
  uint4* sWt = (uint4*)(arena + SX_B);

  const int bx = blockIdx.x;              // 1024 blocks
  const int idx = bx >> 3;
  const int b = 2 * (bx & 7) + (idx >> 6);
  const int h0 = (idx & 63) * 2;
  const int tid = threadIdx.x;
  const int lane = tid & 63;
  const int wid = tid >> 6;               // 0..7
  const int row = wid >> 2;               // output row h0+row
  const int m0 = (wid & 3) * 32;          // pixel base within row
  const int l15 = lane & 15;
  const int lg = lane >> 4;

  f32x4 acc[2][NFRAG];
#pragma unroll
  for (int mf = 0; mf < 2; ++mf)
#pragma unroll
    for (int nf = 0; nf < NFRAG; ++nf) acc[mf][nf] = {0.f, 0.f, 0.f, 0.f};

  // zero chunk-invariant pad slots: wl=0 and wl=129, all 4 tilerows, both bufs
  if (tid < 64) {
    int bi = tid >> 5, tr = (tid >> 3) & 3, wz = (tid >> 2) & 1, gq = tid & 3;
    int wl = wz ? 129 : 0;
    *reinterpret_cast<uint4*>(&sXa[bi * SXN + ((tr * 130 + wl) * 4 + gq) * 8]) =
        make_uint4(0u, 0u, 0u, 0u);
  }
  // zero OOB rows (boundary blocks only); loads skip them every chunk
  if (h0 == 0 || h0 == 126) {
    const int trz = (h0 == 0) ? 0 : 3;
#pragma unroll
    for (int e = 0; e < 2; ++e) {
      int u = tid + e * 512;
      int bi = u >> 9, k = u & 511;
      *reinterpret_cast<uint4*>(&sXa[bi * SXN + ((trz * 130 + 1) * 4 + k) * 8]) =
          make_uint4(0u, 0u, 0u, 0u);
    }
  }

  // async stage act chunk c into buffer bi: per wave 4 x glds16
  auto stage = [&](int c, int bi) {
    const int c0 = c * 32;
    const ushort* src;
    int cst, coff;
    if (CB == 0 || c0 < CA) { src = xa; cst = CA; coff = c0; }
    else                    { src = xb; cst = CB; coff = c0 - CA; }
    const int tr = wid >> 1;            // tilerow 0..3
    const int gh = h0 - 1 + tr;
    if ((unsigned)gh < 128u) {
      const ushort* rowp = src + ((long)(b * 128 + gh) * 128) * cst + coff;
#pragma unroll
      for (int t = 0; t < 4; ++t) {
        int s = (wid & 1) * 4 + t;      // segment 0..7 within tilerow
        int u = s * 64 + lane;          // uint4 idx within row region (0..511)
        int wl = 1 + (u >> 2);
        int gq = lane & 3;
        int sw = (wl + (wl >> 2)) & 3;
        const ushort* gp = rowp + (long)(wl - 1) * cst + (gq ^ sw) * 8;
        ushort* lp = &sXa[bi * SXN + ((tr * 130 + 1) * 4 + s * 64) * 8];
        glds16(gp, lp);
      }
    }
  };

  uint4 wtr[WI];
  auto wt_load = [&](int c) {
    const uint4* src = wp + (size_t)c * WTQ;
#pragma unroll
    for (int i = 0; i < WI; ++i) {
      int e = tid + i * 512;
      if ((WTQ & 511) == 0 || e < WTQ) wtr[i] = src[e];
    }
  };
  auto wt_write = [&]() {
#pragma unroll
    for (int i = 0; i < WI; ++i) {
      int e = tid + i * 512;
      if ((WTQ & 511) == 0 || e < WTQ) sWt[e] = wtr[i];
    }
  };

  wt_load(0);
  wt_write();
  stage(0, 0);
  __syncthreads();  // act0 staged (vmcnt drained), wt0 in LDS

  for (int c = 0; c < CHUNKS; ++c) {
    if (c + 1 < CHUNKS) {
      wt_load(c + 1);                 // global->reg, lands during compute
      stage(c + 1, (c + 1) & 1);      // async glds16
    }
    const int bi = c & 1;
    const ushort* wbase = (const ushort*)sWt;
#pragma unroll
    for (int rs = 0; rs < 9; ++rs) {
      const int r = rs / 3, s = rs % 3;
      const int tr = row + r;
      bf16x8 afr[2];
#pragma unroll
      for (int mf = 0; mf < 2; ++mf) {
        int wl = m0 + mf * 16 + l15 + s;
        int sw = (wl + (wl >> 2)) & 3;
        afr[mf] = *reinterpret_cast<const bf16x8*>(
            &sXa[bi * SXN + ((tr * 130 + wl) * 4 + (lg ^ sw)) * 8]);
      }
      const ushort* wrow = wbase + (size_t)(rs * NFRAG) * 64 * 8;
#pragma unroll
      for (int nf = 0; nf < NFRAG; ++nf) {
        bf16x8 bfr = *reinterpret_cast<const bf16x8*>(wrow + (nf * 64 + lane) * 8);
        acc[0][nf] = __builtin_amdgcn_mfma_f32_16x16x32_bf16(afr[0], bfr, acc[0][nf], 0, 0, 0);
        acc[1][nf] = __builtin_amdgcn_mfma_f32_16x16x32_bf16(afr[1], bfr, acc[1][nf], 0, 0, 0);
      }
    }
    __syncthreads();                  // readers done with sWt; act(c+1)/wt regs landed
    if (c + 1 < CHUNKS) wt_write();
    __syncthreads();                  // sWt(c+1) visible
  }

  // epilogue: overlay arena (all staging dead after final barriers)
  if (!PLANAR) {
    ushort* sO = (ushort*)arena;  // [px2][ch], stride SO_STRIDE; px2 = row*128+px
#pragma unroll
    for (int nf = 0; nf < NFRAG; ++nf) {
      float bs = bias[nf * 16 + l15];
#pragma unroll
      for (int mf = 0; mf < 2; ++mf) {
        int px2 = row * 128 + m0 + mf * 16 + lg * 4;
#pragma unroll
        for (int j = 0; j < 4; ++j) {
          float v = acc[mf][nf][j] + bs;
          if (RELU) v = fmaxf(v, 0.f);
          sO[(px2 + j) * SO_STRIDE + nf * 16 + l15] = f2bf_bits(v);
        }
      }
    }
    __syncthreads();
    constexpr int QPP = COUT / 8;  // uint4 per pixel
    uint4* dst = reinterpret_cast<uint4*>((ushort*)outv + ((long)(b * 128 + h0) * 128) * COUT);
#pragma unroll
    for (int t0 = 0; t0 < 2 * 128 * QPP / 512; ++t0) {
      int t = t0 * 512 + tid;
      int px2 = t / QPP;
      int ch0 = (t & (QPP - 1)) * 8;
      union { uint4 qq; ushort ss[8]; } pk;
#pragma unroll
      for (int k = 0; k < 8; ++k) pk.ss[k] = sO[px2 * SO_STRIDE + ch0 + k];
      dst[t] = pk.qq;
    }
  } else {
    float* sF = (float*)arena;  // [ch][r][px]
    if (l15 < 2) {
#pragma unroll
      for (int mf = 0; mf < 2; ++mf) {
        int pxb = m0 + mf * 16 + lg * 4;
#pragma unroll
        for (int j = 0; j < 4; ++j)
          sF[(l15 * 2 + row) * 128 + pxb + j] = acc[mf][0][j] + bias[l15];
      }
    }
    __syncthreads();
    float* out = (float*)outv;
    if (tid < 128) {
      int ch = tid >> 6, r = (tid >> 5) & 1, qx = tid & 31;
      *reinterpret_cast<float4*>(&out[((long)(b * 2 + ch) * 128 + h0 + r) * 128 + qx * 4]) =
          *reinterpret_cast<float4*>(&sF[(ch * 2 + r) * 128 + qx * 4]);
    }
  }
}

extern "C" void kernel_launch(void* const* d_in, const int* in_sizes, int n_in,
                              void* d_out, int out_size, void* d_ws, size_t ws_size,
                              hipStream_t stream) {
  (void)in_sizes; (void)n_in; (void)out_size; (void)ws_size;
  const float* f1 = (const float*)d_in[0];
  const float* f2 = (const float*)d_in[1];
  const float* w1 = (const float*)d_in[2];
  const float* b1 = (const float*)d_in[3];
  const float* w2 = (const float*)d_in[4];
  const float* b2 = (const float*)d_in[5];
  const float* w3 = (const float*)d_in[6];
  const float* b3 = (const float*)d_in[7];
  const float* w4 = (const float*)d_in[8];
  const float* b4 = (const float*)d_in[9];

  char* ws = (char*)d_ws;
  size_t off = 0;
  ushort* xf1 = (ushort*)(ws + off); off += (size_t)262144 * 64 * 2;
  ushort* xcv = (ushort*)(ws + off); off += (size_t)262144 * 96 * 2;
  ushort* x1  = (ushort*)(ws + off); off += (size_t)262144 * 128 * 2;
  ushort* x2  = (ushort*)(ws + off); off += (size_t)262144 * 64 * 2;
  uint4* wp1 = (uint4*)(ws + off); off += (size_t)5 * 9 * 8 * 64 * 16;
  uint4* wp2 = (uint4*)(ws + off); off += (size_t)4 * 9 * 4 * 64 * 16;
  uint4* wp3 = (uint4*)(ws + off); off += (size_t)2 * 9 * 2 * 64 * 16;
  uint4* wp4 = (uint4*)(ws + off); off += (size_t)1 * 9 * 1 * 64 * 16;
  ushort* x3 = xf1;  // alias: xf1 fully consumed by conv1 before conv3 writes

  prep_w_kernel<<<90, 256, 0, stream>>>(w1, wp1, 145, 128, 5, 8);
  prep_w_kernel<<<36, 256, 0, stream>>>(w2, wp2, 128, 64, 4, 4);
  prep_w_kernel<<<9, 256, 0, stream>>>(w3, wp3, 64, 32, 2, 2);
  prep_w_kernel<<<3, 256, 0, stream>>>(w4, wp4, 32, 2, 1, 1);

  pack_f1_kernel<<<2048, 256, 0, stream>>>(f1, xf1);
  cost_volume_kernel<<<1024, 256, 0, stream>>>(f1, f2, xcv);

  conv_mfma_kernel<64, 96, 128, true, false><<<1024, 512, 0, stream>>>(xf1, xcv, wp1, b1, x1);
  conv_mfma_kernel<128, 0, 64, true, false><<<1024, 512, 0, stream>>>(x1, x1, wp2, b2, x2);
  conv_mfma_kernel<64, 0, 32, true, false><<<1024, 512, 0, stream>>>(x2, x2, wp3, b3, x3);
  conv_mfma_kernel<32, 0, 16, false, true><<<1024, 512, 0, stream>>>(x3, x3, wp4, b4, d_out);
}

// Round 10
// 332.186 us; speedup vs baseline: 1.8237x; 1.4039x over previous
//
#include <hip/hip_runtime.h>

// B=16, H=W=128. Compact NHWC bf16: xf1 64ch, xcv 96ch (81 cv + 15 zero),
// x1 128ch, x2 64ch, x3 32ch. Output [B,2,H,W] fp32 planar.

typedef __bf16 bf16x8 __attribute__((ext_vector_type(8)));
typedef float f32x4 __attribute__((ext_vector_type(4)));

__device__ __forceinline__ unsigned short f2bf_bits(float f) {
  unsigned int u = __float_as_uint(f);
  unsigned int r = (u + 0x7FFFu + ((u >> 16) & 1u)) >> 16;  // RNE
  return (unsigned short)r;
}

__device__ __forceinline__ void glds16(const ushort* gp, ushort* lp) {
  __builtin_amdgcn_global_load_lds((const __attribute__((address_space(1))) void*)gp,
                                   (__attribute__((address_space(3))) void*)lp, 16, 0, 0);
}

// ---------------- weight prepack: OIHW fp32 -> B-fragment lane order bf16 ----
__global__ void prep_w_kernel(const float* __restrict__ w, uint4* __restrict__ wp,
                              int CIN, int COUT, int CHUNKS, int NFRAG) {
  int idx = blockIdx.x * 256 + threadIdx.x;
  int total = CHUNKS * 9 * NFRAG * 64;
  if (idx >= total) return;
  int lane = idx & 63;
  int fi = idx >> 6;
  int nf = fi % NFRAG;
  int t = fi / NFRAG;
  int rs = t % 9;
  int c = t / 9;
  int co = nf * 16 + (lane & 15);
  int cib = c * 32 + (lane >> 4) * 8;
  union { uint4 q; ushort s[8]; } pk;
#pragma unroll
  for (int e = 0; e < 8; ++e) {
    int ci = cib + e;
    float v = (ci < CIN && co < COUT) ? w[(co * CIN + ci) * 9 + rs] : 0.f;
    pk.s[e] = f2bf_bits(v);
  }
  wp[idx] = pk.q;
}

// ---------------- f1 pack: NCHW fp32 -> compact NHWC bf16 (64 ch) -----------
__global__ __launch_bounds__(256) void pack_f1_kernel(const float* __restrict__ f1,
                                                      ushort* __restrict__ xf1) {
  __shared__ float tile[64][132];
  const int bid = blockIdx.x;
  const int h = bid & 127, b = bid >> 7;
  const int tid = threadIdx.x;
  for (int e = tid; e < 64 * 128; e += 256) {
    int c = e >> 7, w = e & 127;
    tile[c][w] = f1[((b * 64 + c) * 128 + h) * 128 + w];
  }
  __syncthreads();
  const int px = tid >> 1, cgb = (tid & 1) * 4;
  const long base = ((long)(b * 128 + h) * 128 + px) * 64;
#pragma unroll
  for (int e = 0; e < 4; ++e) {
    int c0 = (cgb + e) * 8;
    union { uint4 q; ushort s[8]; } pk;
#pragma unroll
    for (int k = 0; k < 8; ++k) pk.s[k] = f2bf_bits(tile[c0 + k][px]);
    *reinterpret_cast<uint4*>(&xf1[base + c0]) = pk.q;
  }
}

// ---------------- cost volume -> xcv compact NHWC (96 ch) -------------------
__global__ __launch_bounds__(256)
void cost_volume_kernel(const float* __restrict__ f1,
                        const float* __restrict__ f2,
                        ushort* __restrict__ xcv) {
  const int bx = blockIdx.x;           // 1024 blocks
  const int idx = bx >> 3;
  const int b = 2 * (bx & 7) + (idx >> 6);
  const int h0 = (idx & 63) * 2;
  const int tid = threadIdx.x;
  const int q = tid & 31;              // pixel quad: px 4q..4q+3
  const int rho = (tid >> 5) & 1;      // output row h0+rho
  const int g = tid >> 6;              // wave id

  __shared__ float arena[12480];

  float accF[2][9][4];
  float accP[3][4];
#pragma unroll
  for (int s = 0; s < 2; ++s)
#pragma unroll
    for (int jj = 0; jj < 9; ++jj)
#pragma unroll
      for (int e = 0; e < 4; ++e) accF[s][jj][e] = 0.f;
#pragma unroll
  for (int t = 0; t < 3; ++t)
#pragma unroll
    for (int e = 0; e < 4; ++e) accP[t][e] = 0.f;

  float st[13];

  auto stage = [&](int c) {
    const int cc = c * 2;
#pragma unroll
    for (int i = 0; i < 13; ++i) {
      int e = tid + i * 256;
      float v = 0.f;
      if (e < 2720) {
        int ci = e / 1360;
        int rem = e - ci * 1360;
        int a = rem / 136;
        int k = rem - a * 136;
        int gh = h0 - 4 + a, gw = k - 4;
        if ((unsigned)gh < 128u && (unsigned)gw < 128u)
          v = f2[((b * 64 + cc + ci) * 128 + gh) * 128 + gw];
      } else if (e < 3232) {
        int e2 = e - 2720;
        int ci = e2 >> 8, rr = (e2 >> 7) & 1, ww = e2 & 127;
        v = f1[((b * 64 + cc + ci) * 128 + h0 + rr) * 128 + ww];
      }
      st[i] = v;
    }
  };
  auto commit = [&](int bi) {
    float* bufp = arena + bi * 3232;
#pragma unroll
    for (int i = 0; i < 13; ++i) {
      int e = tid + i * 256;
      if (e < 3232) bufp[e] = st[i];
    }
  };

  stage(0);
  commit(0);

  for (int c = 0; c < 32; ++c) {
    __syncthreads();
    if (c < 31) stage(c + 1);
    const float* bufc = arena + (c & 1) * 3232;
#pragma unroll
    for (int ci = 0; ci < 2; ++ci) {
      const float* bp = bufc + ci * 1360;
      float4 f1q = *reinterpret_cast<const float4*>(bufc + 2720 + ci * 256 + rho * 128 + 4 * q);
      const float* f1e = &f1q.x;
#pragma unroll
      for (int s = 0; s < 2; ++s) {
        int a = rho + 8 - (2 * g + s);
        const float* rp = bp + a * 136 + 4 * q;
        float4 A = *reinterpret_cast<const float4*>(rp);
        float4 Bv = *reinterpret_cast<const float4*>(rp + 4);
        float4 Cv = *reinterpret_cast<const float4*>(rp + 8);
        float ev[12] = {A.x, A.y, A.z, A.w, Bv.x, Bv.y, Bv.z, Bv.w, Cv.x, Cv.y, Cv.z, Cv.w};
#pragma unroll
        for (int jj = 0; jj < 9; ++jj)
#pragma unroll
          for (int e = 0; e < 4; ++e)
            accF[s][jj][e] += f1e[e] * ev[8 - jj + e];
      }
      {
        const float* rp = bp + rho * 136 + 4 * q;
        if (g < 2) {
          float4 A = *reinterpret_cast<const float4*>(rp + 4);
          float4 Bv = *reinterpret_cast<const float4*>(rp + 8);
          float pv[8] = {A.x, A.y, A.z, A.w, Bv.x, Bv.y, Bv.z, Bv.w};
          if (g == 0) {
#pragma unroll
            for (int e = 0; e < 4; ++e) {
              accP[0][e] += f1e[e] * pv[4 + e];
              accP[1][e] += f1e[e] * pv[3 + e];
              accP[2][e] += f1e[e] * pv[2 + e];
            }
          } else {
#pragma unroll
            for (int e = 0; e < 4; ++e) {
              accP[0][e] += f1e[e] * pv[1 + e];
              accP[1][e] += f1e[e] * pv[e];
            }
          }
        } else {
          float4 A = *reinterpret_cast<const float4*>(rp);
          float4 Bv = *reinterpret_cast<const float4*>(rp + 4);
          float pv[8] = {A.x, A.y, A.z, A.w, Bv.x, Bv.y, Bv.z, Bv.w};
          if (g == 2) {
#pragma unroll
            for (int e = 0; e < 4; ++e) {
              accP[0][e] += f1e[e] * pv[3 + e];
              accP[1][e] += f1e[e] * pv[2 + e];
            }
          } else {
#pragma unroll
            for (int e = 0; e < 4; ++e) {
              accP[0][e] += f1e[e] * pv[1 + e];
              accP[1][e] += f1e[e] * pv[e];
            }
          }
        }
      }
    }
    if (c < 31) commit((c + 1) & 1);
  }

  __syncthreads();  // all compute done; overlay output staging
  ushort* sO = (ushort*)arena;  // [(r*96+ch)*130 + px]
  const float inv = 1.0f / 64.0f;
#pragma unroll
  for (int s = 0; s < 2; ++s) {
    int ch = (2 * g + s) * 9;
#pragma unroll
    for (int jj = 0; jj < 9; ++jj) {
      uint lo = (uint)f2bf_bits(accF[s][jj][0] * inv) | ((uint)f2bf_bits(accF[s][jj][1] * inv) << 16);
      uint hi = (uint)f2bf_bits(accF[s][jj][2] * inv) | ((uint)f2bf_bits(accF[s][jj][3] * inv) << 16);
      ushort* d = &sO[(rho * 96 + ch + jj) * 130 + 4 * q];
      *reinterpret_cast<uint*>(d) = lo;
      *reinterpret_cast<uint*>(d + 2) = hi;
    }
  }
  {
    const int npart = (g == 0) ? 3 : 2;
    const int chbase = 72 + ((g == 0) ? 0 : (g == 1) ? 3 : (g == 2) ? 5 : 7);
#pragma unroll
    for (int t = 0; t < 3; ++t) {
      if (t < npart) {
        uint lo = (uint)f2bf_bits(accP[t][0] * inv) | ((uint)f2bf_bits(accP[t][1] * inv) << 16);
        uint hi = (uint)f2bf_bits(accP[t][2] * inv) | ((uint)f2bf_bits(accP[t][3] * inv) << 16);
        ushort* d = &sO[(rho * 96 + chbase + t) * 130 + 4 * q];
        *reinterpret_cast<uint*>(d) = lo;
        *reinterpret_cast<uint*>(d + 2) = hi;
      }
    }
  }
  for (int e = tid; e < 1920; e += 256) {  // zero ch 81..95, both rows
    int r = e / 960;
    int rem = e - r * 960;
    int ch = 81 + (rem >> 6);
    int pxh = rem & 63;
    *reinterpret_cast<uint*>(&sO[(r * 96 + ch) * 130 + pxh * 2]) = 0u;
  }
  __syncthreads();

  // coalesced store: per row 1536 uint4 (128 px x 96 ch); 128 threads x 12 each
  {
    const int r = tid >> 7, u = tid & 127;
    uint4* dst = reinterpret_cast<uint4*>(xcv + ((long)(b * 128 + h0 + r) * 128) * 96);
#pragma unroll
    for (int j = 0; j < 12; ++j) {
      int t8 = 128 * j + u;           // 0..1535
      int px = t8 / 12;               // 0..127
      int ch0 = (t8 - px * 12) * 8;   // 0..88
      union { uint4 qq; ushort ss[8]; } pk;
#pragma unroll
      for (int k = 0; k < 8; ++k) pk.ss[k] = sO[(r * 96 + ch0 + k) * 130 + px];
      dst[t8] = pk.qq;
    }
  }
}

// ---------------- implicit-GEMM 3x3 conv via bf16 MFMA ----------------------
// 512 thr = 8 waves; wave = 1 output row x 32 px (2 M-frags) x all N-frags.
// Activations: glds16 double-buffer (pre-swizzled source, linear dest).
// Weights: glds16 into single LDS buffer (NO register staging -> no spill);
// per chunk: stage_act(c+1) || compute(c) -> barrier -> stage_wt(c+1) -> barrier.
// Inner loop is pure ds_read_b128 + MFMA (both operands from LDS).
template <int CA, int CB, int COUT, bool RELU, bool PLANAR>
__global__ __launch_bounds__(512, 2)
void conv_mfma_kernel(const ushort* __restrict__ xa, const ushort* __restrict__ xb,
                      const uint4* __restrict__ wp, const float* __restrict__ bias,
                      void* __restrict__ outv) {
  constexpr int CHUNKS = (CA + CB) / 32;
  constexpr int NFRAG = COUT / 16;
  constexpr int SXN = 4 * 130 * 32;              // ushorts per act buffer
  constexpr int WTQ = 9 * NFRAG * 64;            // uint4 per weight chunk
  constexpr int WI = (WTQ + 511) / 512;          // per-thread glds16 count
  constexpr int SO_STRIDE = COUT + 4;
  constexpr int STAGE_B = PLANAR ? 2048 : 2 * 128 * SO_STRIDE * 2;
  constexpr int SX_B = 2 * SXN * 2;              // 66560
  constexpr int BASE_B = SX_B + WTQ * 16;        // act dbuf + wt buf
  constexpr int ARENA_B = STAGE_B > BASE_B ? STAGE_B : BASE_B;

  __shared__ __align__(16) char arena[ARENA_B];
  ushort* sXa = (ushort*)arena;
  ushort* sWt = (ushort*)(arena + SX_B);

  const int bx = blockIdx.x;              // 1024 blocks
  const int idx = bx >> 3;
  const int b = 2 * (bx & 7) + (idx >> 6);
  const int h0 = (idx & 63) * 2;
  const int tid = threadIdx.x;
  const int lane = tid & 63;
  const int wid = tid >> 6;               // 0..7
  const int row = wid >> 2;               // output row h0+row
  const int m0 = (wid & 3) * 32;          // pixel base within row
  const int l15 = lane & 15;
  const int lg = lane >> 4;

  f32x4 acc[2][NFRAG];
#pragma unroll
  for (int mf = 0; mf < 2; ++mf)
#pragma unroll
    for (int nf = 0; nf < NFRAG; ++nf) acc[mf][nf] = {0.f, 0.f, 0.f, 0.f};

  // zero chunk-invariant pad slots: wl=0 and wl=129, all 4 tilerows, both bufs
  if (tid < 64) {
    int bi = tid >> 5, tr = (tid >> 3) & 3, wz = (tid >> 2) & 1, gq = tid & 3;
    int wl = wz ? 129 : 0;
    *reinterpret_cast<uint4*>(&sXa[bi * SXN + ((tr * 130 + wl) * 4 + gq) * 8]) =
        make_uint4(0u, 0u, 0u, 0u);
  }
  // zero OOB rows (boundary blocks only); loads skip them every chunk
  if (h0 == 0 || h0 == 126) {
    const int trz = (h0 == 0) ? 0 : 3;
#pragma unroll
    for (int e = 0; e < 2; ++e) {
      int u = tid + e * 512;
      int bi = u >> 9, k = u & 511;
      *reinterpret_cast<uint4*>(&sXa[bi * SXN + ((trz * 130 + 1) * 4 + k) * 8]) =
          make_uint4(0u, 0u, 0u, 0u);
    }
  }

  // async stage act chunk c into buffer bi: per wave 4 x glds16
  auto stage = [&](int c, int bi) {
    const int c0 = c * 32;
    const ushort* src;
    int cst, coff;
    if (CB == 0 || c0 < CA) { src = xa; cst = CA; coff = c0; }
    else                    { src = xb; cst = CB; coff = c0 - CA; }
    const int tr = wid >> 1;            // tilerow 0..3
    const int gh = h0 - 1 + tr;
    if ((unsigned)gh < 128u) {
      const ushort* rowp = src + ((long)(b * 128 + gh) * 128) * cst + coff;
#pragma unroll
      for (int t = 0; t < 4; ++t) {
        int s = (wid & 1) * 4 + t;      // segment 0..7 within tilerow
        int u = s * 64 + lane;          // uint4 idx within row region (0..511)
        int wl = 1 + (u >> 2);
        int gq = lane & 3;
        int sw = (wl + (wl >> 2)) & 3;
        const ushort* gp = rowp + (long)(wl - 1) * cst + (gq ^ sw) * 8;
        ushort* lp = &sXa[bi * SXN + ((tr * 130 + 1) * 4 + s * 64) * 8];
        glds16(gp, lp);
      }
    }
  };

  // async stage weight chunk c into sWt: linear glds16, no registers
  auto stage_wt = [&](int c) {
    const ushort* src = (const ushort*)(wp + (size_t)c * WTQ);
#pragma unroll
    for (int i = 0; i < WI; ++i) {
      int e = tid + i * 512;
      if ((WTQ & 511) == 0 || e < WTQ)
        glds16(src + e * 8, sWt + (size_t)(tid & ~63) * 8 + (size_t)(i * 512) * 8);
    }
  };

  stage(0, 0);
  stage_wt(0);
  __syncthreads();  // vmcnt drained: act0 + wt0 in LDS

  for (int c = 0; c < CHUNKS; ++c) {
    if (c + 1 < CHUNKS) stage(c + 1, (c + 1) & 1);  // act prefetch under compute
    const int bi = c & 1;
#pragma unroll
    for (int rs = 0; rs < 9; ++rs) {
      const int r = rs / 3, s = rs % 3;
      const int tr = row + r;
      bf16x8 afr[2];
#pragma unroll
      for (int mf = 0; mf < 2; ++mf) {
        int wl = m0 + mf * 16 + l15 + s;
        int sw = (wl + (wl >> 2)) & 3;
        afr[mf] = *reinterpret_cast<const bf16x8*>(
            &sXa[bi * SXN + ((tr * 130 + wl) * 4 + (lg ^ sw)) * 8]);
      }
      const ushort* wrow = sWt + (size_t)(rs * NFRAG) * 64 * 8;
#pragma unroll
      for (int nf = 0; nf < NFRAG; ++nf) {
        bf16x8 bfr = *reinterpret_cast<const bf16x8*>(wrow + (nf * 64 + lane) * 8);
        acc[0][nf] = __builtin_amdgcn_mfma_f32_16x16x32_bf16(afr[0], bfr, acc[0][nf], 0, 0, 0);
        acc[1][nf] = __builtin_amdgcn_mfma_f32_16x16x32_bf16(afr[1], bfr, acc[1][nf], 0, 0, 0);
      }
    }
    __syncthreads();                  // all waves done reading sWt(c)
    if (c + 1 < CHUNKS) stage_wt(c + 1);
    __syncthreads();                  // vmcnt drain: wt(c+1) + act(c+1) landed
  }

  // epilogue: overlay arena (all staging dead after final barriers)
  if (!PLANAR) {
    ushort* sO = (ushort*)arena;  // [px2][ch], stride SO_STRIDE; px2 = row*128+px
#pragma unroll
    for (int nf = 0; nf < NFRAG; ++nf) {
      float bs = bias[nf * 16 + l15];
#pragma unroll
      for (int mf = 0; mf < 2; ++mf) {
        int px2 = row * 128 + m0 + mf * 16 + lg * 4;
#pragma unroll
        for (int j = 0; j < 4; ++j) {
          float v = acc[mf][nf][j] + bs;
          if (RELU) v = fmaxf(v, 0.f);
          sO[(px2 + j) * SO_STRIDE + nf * 16 + l15] = f2bf_bits(v);
        }
      }
    }
    __syncthreads();
    constexpr int QPP = COUT / 8;  // uint4 per pixel
    uint4* dst = reinterpret_cast<uint4*>((ushort*)outv + ((long)(b * 128 + h0) * 128) * COUT);
#pragma unroll
    for (int t0 = 0; t0 < 2 * 128 * QPP / 512; ++t0) {
      int t = t0 * 512 + tid;
      int px2 = t / QPP;
      int ch0 = (t & (QPP - 1)) * 8;
      union { uint4 qq; ushort ss[8]; } pk;
#pragma unroll
      for (int k = 0; k < 8; ++k) pk.ss[k] = sO[px2 * SO_STRIDE + ch0 + k];
      dst[t] = pk.qq;
    }
  } else {
    float* sF = (float*)arena;  // [ch][r][px]
    if (l15 < 2) {
#pragma unroll
      for (int mf = 0; mf < 2; ++mf) {
        int pxb = m0 + mf * 16 + lg * 4;
#pragma unroll
        for (int j = 0; j < 4; ++j)
          sF[(l15 * 2 + row) * 128 + pxb + j] = acc[mf][0][j] + bias[l15];
      }
    }
    __syncthreads();
    float* out = (float*)outv;
    if (tid < 128) {
      int ch = tid >> 6, r = (tid >> 5) & 1, qx = tid & 31;
      *reinterpret_cast<float4*>(&out[((long)(b * 2 + ch) * 128 + h0 + r) * 128 + qx * 4]) =
          *reinterpret_cast<float4*>(&sF[(ch * 2 + r) * 128 + qx * 4]);
    }
  }
}

extern "C" void kernel_launch(void* const* d_in, const int* in_sizes, int n_in,
                              void* d_out, int out_size, void* d_ws, size_t ws_size,
                              hipStream_t stream) {
  (void)in_sizes; (void)n_in; (void)out_size; (void)ws_size;
  const float* f1 = (const float*)d_in[0];
  const float* f2 = (const float*)d_in[1];
  const float* w1 = (const float*)d_in[2];
  const float* b1 = (const float*)d_in[3];
  const float* w2 = (const float*)d_in[4];
  const float* b2 = (const float*)d_in[5];
  const float* w3 = (const float*)d_in[6];
  const float* b3 = (const float*)d_in[7];
  const float* w4 = (const float*)d_in[8];
  const float* b4 = (const float*)d_in[9];

  char* ws = (char*)d_ws;
  size_t off = 0;
  ushort* xf1 = (ushort*)(ws + off); off += (size_t)262144 * 64 * 2;
  ushort* xcv = (ushort*)(ws + off); off += (size_t)262144 * 96 * 2;
  ushort* x1  = (ushort*)(ws + off); off += (size_t)262144 * 128 * 2;
  ushort* x2  = (ushort*)(ws + off); off += (size_t)262144 * 64 * 2;
  uint4* wp1 = (uint4*)(ws + off); off += (size_t)5 * 9 * 8 * 64 * 16;
  uint4* wp2 = (uint4*)(ws + off); off += (size_t)4 * 9 * 4 * 64 * 16;
  uint4* wp3 = (uint4*)(ws + off); off += (size_t)2 * 9 * 2 * 64 * 16;
  uint4* wp4 = (uint4*)(ws + off); off += (size_t)1 * 9 * 1 * 64 * 16;
  ushort* x3 = xf1;  // alias: xf1 fully consumed by conv1 before conv3 writes

  prep_w_kernel<<<90, 256, 0, stream>>>(w1, wp1, 145, 128, 5, 8);
  prep_w_kernel<<<36, 256, 0, stream>>>(w2, wp2, 128, 64, 4, 4);
  prep_w_kernel<<<9, 256, 0, stream>>>(w3, wp3, 64, 32, 2, 2);
  prep_w_kernel<<<3, 256, 0, stream>>>(w4, wp4, 32, 2, 1, 1);

  pack_f1_kernel<<<2048, 256, 0, stream>>>(f1, xf1);
  cost_volume_kernel<<<1024, 256, 0, stream>>>(f1, f2, xcv);

  conv_mfma_kernel<64, 96, 128, true, false><<<1024, 512, 0, stream>>>(xf1, xcv, wp1, b1, x1);
  conv_mfma_kernel<128, 0, 64, true, false><<<1024, 512, 0, stream>>>(x1, x1, wp2, b2, x2);
  conv_mfma_kernel<64, 0, 32, true, false><<<1024, 512, 0, stream>>>(x2, x2, wp3, b3, x3);
  conv_mfma_kernel<32, 0, 16, false, true><<<1024, 512, 0, stream>>>(x3, x3, wp4, b4, d_out);
}